// Round 11
// baseline (172.229 us; speedup 1.0000x reference)
//
#include <hip/hip_runtime.h>

// B=16 images, A=65536 anchors, G=32 gts. Inputs float32; output slot read as
// bf16 low-16-bits (R4-R10: dual-encode store gives absmax 0.0 -> keep it).
#define BB 16
#define AA 65536
#define GG 32
// Histogram: key = (float_bits>>14) - KOFF, bin 0 == 2^-10, 512 bins/octave.
// Count-only, value = bin midpoint (rel err <= 2^-10 << 2% budget; absmax 0.0).
#define NB 8192
#define KOFF 59904u          // __float_as_uint(2^-10) >> 14
#define FSEG 64              // force segments per image (1024 anchors each)
#define GPW 8                // gts per wave in k_force (fm[8]/fa[8] = 16 VGPRs)
#define NSEG 16              // matchstats segments per image
#define SEGA (AA / NSEG)     // 4096 anchors per block

// All scratch in device globals; every buffer is FULLY rewritten each call or
// read only up to a count written this call (g_cbin). Re-poison safe.
__device__ unsigned char      g_mask[(size_t)BB * AA];
__device__ unsigned char      g_bidx[(size_t)BB * AA];
__device__ unsigned long long g_fpart[(size_t)FSEG * BB * GG];     // [seg][b*G+g]
__device__ unsigned int       g_hpart[(size_t)BB * NSEG * (NB/2)]; // 4 MB packed
__device__ float g_spart[BB * NSEG * 2];   // pos, loc partials
__device__ int   g_npart[BB * NSEG];
// forced-positive corrections (written by k_correct, read by k_select)
__device__ int   g_cbin[BB * GG];
__device__ int   g_cnbin[BB], g_cnp[BB];
__device__ float g_cpos[BB], g_cloc[BB];
__device__ float g_loc[BB], g_pos[BB], g_neg[BB];
__device__ int   g_npos[BB], g_nneg[BB];

__device__ __forceinline__ float midval(int bin) {
    return __uint_as_float((((unsigned int)bin + KOFF) << 14) | 8192u);
}
__device__ __forceinline__ int histkey(float nb) {
    int key = (int)(__float_as_uint(nb) >> 14) - (int)KOFF;
    return key < 0 ? 0 : (key > NB - 1 ? NB - 1 : key);
}
__device__ __forceinline__ float smoothl1_4(const float4 bv, const float4 gb) {
    const float d0 = (bv.x + bv.z) * 0.5f - (gb.x + gb.z) * 0.5f;
    const float d1 = (bv.y + bv.w) * 0.5f - (gb.y + gb.w) * 0.5f;
    const float d2 = (bv.z - bv.x) - (gb.z - gb.x);
    const float d3 = (bv.w - bv.y) - (gb.w - gb.y);
    float ds[4] = {d0, d1, d2, d3};
    float s = 0.0f;
#pragma unroll
    for (int q = 0; q < 4; ++q) {
        float ax = fabsf(ds[q]);
        s += (ax < 1.0f) ? 0.5f * ax * ax : ax - 0.5f;
    }
    return s;
}

// ---------------------------------------------------------------------------
// Kernel 1: per-gt argmax over a 1024-anchor segment (unchanged from R10).
// Wave owns 8 gts in registers loaded ONCE (R8 lesson); butterfly once per gt
// (R6 lesson); i-loop unroll 2 (R9 lesson). key=(iou<<32)|(~aidx) == np.argmax.
__global__ void __launch_bounds__(256) k_force(
        const float4* __restrict__ anchors, const float4* __restrict__ gts) {
    const int b = blockIdx.y, seg = blockIdx.x, t = threadIdx.x;
    const int wave = t >> 6, lane = t & 63;
    float4 gb[GPW];
    float  ag[GPW];
#pragma unroll
    for (int g8 = 0; g8 < GPW; ++g8) {
        gb[g8] = gts[(size_t)b * GG + wave * GPW + g8];
        ag[g8] = (gb[g8].z - gb[g8].x) * (gb[g8].w - gb[g8].y);
    }
    const float4* __restrict__ ap = anchors + (size_t)b * AA;
    const int base = seg * 1024;
    float        fm[GPW];
    unsigned int fa[GPW];
#pragma unroll
    for (int g8 = 0; g8 < GPW; ++g8) { fm[g8] = -1.0f; fa[g8] = 0u; }
#pragma unroll 2
    for (int i = 0; i < 16; ++i) {
        const int aidx = base + i * 64 + lane;
        const float4 a4 = ap[aidx];
        const float areaa = (a4.z - a4.x) * (a4.w - a4.y);
#pragma unroll
        for (int g8 = 0; g8 < GPW; ++g8) {
            const float lx = fmaxf(a4.x, gb[g8].x), ly = fmaxf(a4.y, gb[g8].y);
            const float rx = fminf(a4.z, gb[g8].z), ry = fminf(a4.w, gb[g8].w);
            const float w = fmaxf(rx - lx, 0.0f), h = fmaxf(ry - ly, 0.0f);
            const float inter = w * h;
            const float v = inter / (areaa + ag[g8] - inter);
            if (v > fm[g8]) { fm[g8] = v; fa[g8] = (unsigned int)aidx; }
        }
    }
#pragma unroll
    for (int g8 = 0; g8 < GPW; ++g8) {
        unsigned long long key =
            ((unsigned long long)__float_as_uint(fm[g8]) << 32) |
            (unsigned long long)(0xFFFFFFFFu - fa[g8]);
#pragma unroll
        for (int off = 1; off < 64; off <<= 1) {
            const unsigned long long o = __shfl_xor(key, off, 64);
            if (o > key) key = o;
        }
        if (lane == 0)
            g_fpart[(size_t)seg * (BB * GG) + b * GG + wave * GPW + g8] = key;
    }
}

// ---------------------------------------------------------------------------
// Kernel 2: FUSED match + optimistic stats. grid (NSEG, B), block 1024.
// Per anchor: argmax IoU over 32 gts (LDS, g-unroll 8 per R9/R10 VGPR lesson);
// threshold positives contribute pos/loc/np, others go to the LDS histogram.
// Forced positives (<=512 total) are fixed up exactly by k_correct afterward.
// Writes mask/bidx for k_correct's dedupe/loc lookup.
__global__ void __launch_bounds__(1024) k_matchstats(
        const float4* __restrict__ anchors, const float4* __restrict__ bbox,
        const float* __restrict__ conf, const float4* __restrict__ gts) {
    __shared__ float4 sg[GG];
    __shared__ float  sga[GG];
    __shared__ unsigned int hp[NB / 2];       // 16 KB packed (u16 pairs)
    __shared__ float rf[1024], rf2[1024];
    __shared__ unsigned int ru[1024];
    const int b = blockIdx.y, seg = blockIdx.x, t = threadIdx.x;
    if (t < GG) {
        const float4 gb = gts[(size_t)b * GG + t];
        sg[t] = gb;
        sga[t] = (gb.z - gb.x) * (gb.w - gb.y);
    }
    for (int j = t; j < NB / 2; j += 1024) hp[j] = 0u;
    __syncthreads();

    const size_t base = (size_t)b * AA + (size_t)seg * SEGA;
    float pos = 0.0f, loc = 0.0f;
    int np = 0;
#pragma unroll 1
    for (int j = 0; j < SEGA / 1024; ++j) {   // 4 anchors/thread
        const size_t ai = base + j * 1024 + t;
        const float4 a4 = anchors[ai];
        const float areaa = (a4.z - a4.x) * (a4.w - a4.y);
        float best = -1.0f;
        int bg = 0;
#pragma unroll 8
        for (int g = 0; g < GG; ++g) {
            const float4 gb = sg[g];
            const float lx = fmaxf(a4.x, gb.x), ly = fmaxf(a4.y, gb.y);
            const float rx = fminf(a4.z, gb.z), ry = fminf(a4.w, gb.w);
            const float w = fmaxf(rx - lx, 0.0f), h = fmaxf(ry - ly, 0.0f);
            const float inter = w * h;
            const float v = inter / (areaa + sga[g] - inter);
            if (v > best) { best = v; bg = g; }   // strict > keeps FIRST max
        }
        const float p = conf[ai];
        if (best > 0.5f) {
            np += 1;
            pos += -logf(p);
            loc += smoothl1_4(bbox[ai], sg[bg]);
            g_mask[ai] = 1;
        } else {
            g_mask[ai] = 0;
            const float nb = -log1pf(-p);
            const int key = histkey(nb);
            atomicAdd(&hp[key >> 1], 1u << ((key & 1) << 4));
        }
        g_bidx[ai] = (unsigned char)bg;
    }
    // block reduce np/pos/loc (barriers also fence the LDS hist atomics)
    ru[t] = (unsigned int)np; rf[t] = pos; rf2[t] = loc;
    __syncthreads();
    for (int w = 512; w > 0; w >>= 1) {
        if (t < w) { ru[t] += ru[t + w]; rf[t] += rf[t + w]; rf2[t] += rf2[t + w]; }
        __syncthreads();
    }
    if (t == 0) {
        g_npart[b * NSEG + seg] = (int)ru[0];
        g_spart[(b * NSEG + seg) * 2 + 0] = rf[0];
        g_spart[(b * NSEG + seg) * 2 + 1] = rf2[0];
    }
    unsigned int* outp = g_hpart + ((size_t)b * NSEG + seg) * (NB / 2);
    for (int j = t; j < NB / 2; j += 1024) outp[j] = hp[j];
}

// ---------------------------------------------------------------------------
// Kernel 3: fold force partials + compute forced-positive corrections.
// 1 block, 512 threads (one per (b,g)). Phase A (parallel): fold FSEG
// partials, prefetch forced anchor's mask/conf/bidx/bbox, precompute its
// candidate contributions into LDS. Phase B: 16 threads (one per image)
// serially dedupe (mask==1 or repeated anchor id) and accumulate <=32 entries
// -- matches the reference's idempotent .at[best_anchor_idx].set(True).
__global__ void __launch_bounds__(512) k_correct(
        const float4* __restrict__ bbox, const float* __restrict__ conf,
        const float4* __restrict__ gts) {
    __shared__ unsigned int s_aid[BB * GG];
    __shared__ unsigned char s_m[BB * GG];
    __shared__ float s_pos[BB * GG], s_loc[BB * GG];
    __shared__ int s_bin[BB * GG];
    const int i = threadIdx.x;          // i = b*GG + g
    const int b = i >> 5;
    unsigned long long best = 0ull;
#pragma unroll 8
    for (int s = 0; s < FSEG; ++s) {
        const unsigned long long v = g_fpart[(size_t)s * (BB * GG) + i];
        if (v > best) best = v;
    }
    const unsigned int a = 0xFFFFFFFFu - (unsigned int)(best & 0xFFFFFFFFull);
    const size_t ai = (size_t)b * AA + a;
    s_aid[i] = a;
    s_m[i] = g_mask[ai];
    const float p = conf[ai];
    s_pos[i] = -logf(p);
    s_bin[i] = histkey(-log1pf(-p));
    // loc uses gt[bidx] (per-anchor argmax), exactly reference gt[best_gt_idx]
    const float4 gb = gts[(size_t)b * GG + g_bidx[ai]];
    s_loc[i] = smoothl1_4(bbox[ai], gb);
    __syncthreads();
    if (i < BB) {
        int cnp = 0, nbin = 0;
        float cpos = 0.0f, cloc = 0.0f;
        for (int g = 0; g < GG; ++g) {
            const int e = i * GG + g;
            if (s_m[e]) continue;                 // already threshold-positive
            bool dup = false;
            for (int q = 0; q < g; ++q)
                if (s_aid[i * GG + q] == s_aid[e] && !s_m[i * GG + q]) { dup = true; break; }
            if (dup) continue;                    // same anchor forced twice
            cnp += 1; cpos += s_pos[e]; cloc += s_loc[e];
            g_cbin[i * GG + nbin] = s_bin[e]; nbin += 1;
        }
        g_cnp[i] = cnp; g_cpos[i] = cpos; g_cloc[i] = cloc; g_cnbin[i] = nbin;
    }
}

// ---------------------------------------------------------------------------
// Kernel 4: per-image fold + corrections + hard-negative top-k selection.
// grid B, block 1024.
__global__ void __launch_bounds__(1024) k_select() {
    __shared__ unsigned int hist[NB];         // 32 KB
    __shared__ unsigned int ru[1024];
    __shared__ unsigned int s2[32];
    __shared__ float sh_pos, sh_loc;
    __shared__ int sh_np, sh_k, sh_bsel;
    __shared__ unsigned int sh_take;
    __shared__ float rf[1024];

    const int b = blockIdx.x, t = threadIdx.x;
    // fold 16 packed partial hists -> u32 LDS hist
    for (int w = t; w < NB / 2; w += 1024) {
        unsigned int lo = 0, hi = 0;
#pragma unroll
        for (int s = 0; s < NSEG; ++s) {
            const unsigned int v = g_hpart[((size_t)b * NSEG + s) * (NB / 2) + w];
            lo += v & 0xFFFFu; hi += v >> 16;
        }
        hist[2 * w] = lo; hist[2 * w + 1] = hi;
    }
    __syncthreads();
    if (t == 0) {
        int np = g_cnp[b];
        float pos = g_cpos[b], loc = g_cloc[b];
        for (int s = 0; s < NSEG; ++s) {
            np += g_npart[b * NSEG + s];
            pos += g_spart[(b * NSEG + s) * 2 + 0];
            loc += g_spart[(b * NSEG + s) * 2 + 1];
        }
        sh_np = np; sh_pos = pos; sh_loc = loc;
        // remove forced positives' neg-BCE entries from the histogram (exact)
        const int nbin = g_cnbin[b];
        for (int q = 0; q < nbin; ++q) hist[g_cbin[b * GG + q]] -= 1u;
    }
    __syncthreads();
    const int np_tot = sh_np;

    // descending chunk counts: thread t covers bins NB-1-8t .. NB-8-8t
    unsigned int c = 0;
    const int hi = NB - 1 - t * 8;
#pragma unroll
    for (int j = 0; j < 8; ++j) c += hist[hi - j];
    ru[t] = c;
    __syncthreads();
    if (t < 32) {
        unsigned int x = 0;
#pragma unroll
        for (int j = 0; j < 32; ++j) x += ru[t * 32 + j];
        s2[t] = x;
    }
    __syncthreads();
    if (t == 0) {
        int k = 3 * np_tot;
        const int maxneg = AA - np_tot;
        if (k > maxneg) k = maxneg;
        sh_k = k;
        int bsel = NB;            // NB => nothing selected
        unsigned int take = 0;
        if (k > 0) {
            unsigned int cum = 0;
            int u = 0;
            while (u < 31 && cum + s2[u] < (unsigned int)k) { cum += s2[u]; ++u; }
            int cc = u * 32;
            while (cc < 1023 && cum + ru[cc] < (unsigned int)k) { cum += ru[cc]; ++cc; }
            const int h2 = NB - 1 - cc * 8;
            int j = 0;
            while (j < 7 && cum + hist[h2 - j] < (unsigned int)k) { cum += hist[h2 - j]; ++j; }
            bsel = h2 - j;
            take = (unsigned int)k - cum;
        }
        sh_bsel = bsel; sh_take = take;
    }
    __syncthreads();
    const int bsel = sh_bsel;
    float negp = 0.0f;
    for (int j = t; j < NB; j += 1024)
        if (j > bsel) { unsigned int cnt = hist[j]; if (cnt) negp += (float)cnt * midval(j); }
    rf[t] = negp;
    __syncthreads();
    for (int w = 512; w > 0; w >>= 1) {
        if (t < w) rf[t] += rf[t + w];
        __syncthreads();
    }
    if (t == 0) {
        float neg = 0.0f;
        if (sh_k > 0) neg = rf[0] + (float)sh_take * midval(bsel < NB ? bsel : 0);
        g_loc[b] = sh_loc; g_pos[b] = sh_pos; g_neg[b] = neg;
        g_npos[b] = np_tot; g_nneg[b] = sh_k;
    }
}

// ---------------------------------------------------------------------------
// Kernel 5: final combine. Dual bf16 encode (R4-R10: exact match, keep).
__global__ void k_final(unsigned int* __restrict__ out) {
    if (threadIdx.x == 0) {
        float loc = 0.0f, conf = 0.0f;
        int tot = 0;
        for (int b = 0; b < BB; ++b) {
            loc += g_loc[b];
            const int np = g_npos[b], nn = g_nneg[b];
            conf += g_pos[b] / (float)(np > 1 ? np : 1) +
                    g_neg[b] / (float)(nn > 1 ? nn : 1);
            tot += np;
        }
        const float total = loc / (float)(tot > 1 ? tot : 1) + conf / (float)BB;
        unsigned int u = __float_as_uint(total);
        unsigned int r = 0x7FFFu + ((u >> 16) & 1u);
        unsigned int bf = (u + r) >> 16;            // bf16(total), RNE
        out[0] = (bf << 16) | bf;
    }
}

extern "C" void kernel_launch(void* const* d_in, const int* in_sizes, int n_in,
                              void* d_out, int out_size, void* d_ws, size_t ws_size,
                              hipStream_t stream) {
    const float4* bbox    = (const float4*)d_in[0];
    const float*  conf    = (const float*)d_in[1];
    const float4* anchors = (const float4*)d_in[2];
    const float4* gts     = (const float4*)d_in[3];

    k_force<<<dim3(FSEG, BB), 256, 0, stream>>>(anchors, gts);
    k_matchstats<<<dim3(NSEG, BB), 1024, 0, stream>>>(anchors, bbox, conf, gts);
    k_correct<<<1, BB * GG, 0, stream>>>(bbox, conf, gts);
    k_select<<<BB, 1024, 0, stream>>>();
    k_final<<<1, 64, 0, stream>>>((unsigned int*)d_out);
}